// Round 9
// baseline (908.511 us; speedup 1.0000x reference)
//
#include <hip/hip_runtime.h>
#include <hip/hip_bf16.h>

// QuantizedLinear: out[m,o] = sum_k x[m,k] * (q[o,k]-z[o,g])*s[o,g] + b[o]
// M=8192, K=4096, N=11008. Pass1: dequant W->bf16 (row-major B^T), cvt x->bf16.
// Pass2: 256x256 bf16 GEMM, BK=32, QUAD-buffered LDS (4 x 32KB), ONE barrier
// per K-tile, counted vmcnt(8) (stages of t+2,t+3 stay in flight - T4).
// LDS layout is FRAGMENT-LINEAR: fragment f (A: f=wr*8+m, B: f=wc*4+n) lives at
// bytes f*1024 + lane*16, so every ds_read_b128 is lane-linear over a
// contiguous 1KB run -> ZERO bank conflicts (R8's fr*64B stride aliased mod
// 128B -> 8-way conflict). Achieved by permuting the staging threads' GLOBAL
// source (rule #21: LDS dest and read both linear, source carries the perm):
//   A: thread t fetches row (t>>6)*16+(t&15), kslot (t>>4)&3
//   B: thread t fetches col (t>>8)*64+((t>>6)&3)*16+(t&15), kslot (t>>4)&3
// T1 XCD swizzle, T5 setprio.

#define K_DIM 4096
#define N_DIM 11008
#define M_DIM 8192
#define NGRP 32

typedef __bf16 bf16x8 __attribute__((ext_vector_type(8)));
typedef float f32x4 __attribute__((ext_vector_type(4)));
typedef unsigned short u16x8 __attribute__((ext_vector_type(8)));

__device__ __forceinline__ unsigned short f2bf(float f) {
  unsigned u = __builtin_bit_cast(unsigned, f);
  return (unsigned short)((u + 0x7FFFu + ((u >> 16) & 1u)) >> 16);  // RNE
}

__device__ __forceinline__ void gload_lds16(const void* g, void* l) {
  __builtin_amdgcn_global_load_lds(
      (const __attribute__((address_space(1))) unsigned int*)(unsigned long long)g,
      (__attribute__((address_space(3))) unsigned int*)(unsigned int)(unsigned long long)l,
      16, 0, 0);
}

// ---- pass 1a: x fp32 -> bf16 ----
__global__ __launch_bounds__(256) void cvt_x_kernel(const float4* __restrict__ x4,
                                                    u16x8* __restrict__ xb) {
  int i = blockIdx.x * 256 + threadIdx.x;
  float4 a = x4[2 * i], b = x4[2 * i + 1];
  u16x8 r;
  r[0] = f2bf(a.x); r[1] = f2bf(a.y); r[2] = f2bf(a.z); r[3] = f2bf(a.w);
  r[4] = f2bf(b.x); r[5] = f2bf(b.y); r[6] = f2bf(b.z); r[7] = f2bf(b.w);
  xb[i] = r;
}

// ---- pass 1b: dequant W -> bf16 (row-major [N][K]) ----
__global__ __launch_bounds__(256) void dequant_kernel(const int4* __restrict__ q4,
                                                      const float* __restrict__ scales,
                                                      const float* __restrict__ zeros,
                                                      u16x8* __restrict__ wb) {
  int t = blockIdx.x * 256 + threadIdx.x;
  int o = t >> 9;
  int j8 = t & 511;
  int g = j8 >> 4;
  float s = scales[o * NGRP + g];
  float z = zeros[o * NGRP + g];
  float nzs = -z * s;
  int4 qa = q4[2 * t], qb = q4[2 * t + 1];
  u16x8 r;
  r[0] = f2bf(fmaf((float)qa.x, s, nzs));
  r[1] = f2bf(fmaf((float)qa.y, s, nzs));
  r[2] = f2bf(fmaf((float)qa.z, s, nzs));
  r[3] = f2bf(fmaf((float)qa.w, s, nzs));
  r[4] = f2bf(fmaf((float)qb.x, s, nzs));
  r[5] = f2bf(fmaf((float)qb.y, s, nzs));
  r[6] = f2bf(fmaf((float)qb.z, s, nzs));
  r[7] = f2bf(fmaf((float)qb.w, s, nzs));
  wb[t] = r;
}

// ---- pass 2: 256x256 bf16 GEMM, BK=32, quad-buffer, 1 barrier/tile ----
#define BAR() __builtin_amdgcn_s_barrier()
#define SCHED0() __builtin_amdgcn_sched_barrier(0)

__global__ __launch_bounds__(512, 2) void gemm_kernel(const unsigned short* __restrict__ A,
                                                      const unsigned short* __restrict__ B,
                                                      const float* __restrict__ bias,
                                                      float* __restrict__ C) {
  extern __shared__ unsigned short smem[];
  // sA[buf b] = smem + b*8192 elems (16KB, frag-linear: frag f at f*512 elems)
  // sB[buf b] = smem + 32768 + b*8192

  const int bid = blockIdx.x;
  // T1: 1376 blocks, 1376 % 8 == 0 -> simple bijective XCD swizzle.
  const int swz = (bid & 7) * 172 + (bid >> 3);
  const int tm = swz / 43, tn = swz % 43;

  const int tid = threadIdx.x;
  const int w = tid >> 6, l = tid & 63;
  const int wr = w >> 2, wc = w & 3;

  const int dsto = tid * 8;  // linear LDS dest (elem units)
  // Permuted global sources (see header): instr i=0 covers frags 0..7 (LDS
  // bytes [0,8192)), i=1 (+128 rows/cols) covers frags 8..15.
  const int arow = ((tid >> 6) << 4) + (tid & 15);               // (t>>6)*16+(t&15)
  const int bcol = ((tid >> 8) << 6) + (((tid >> 6) & 3) << 4) + (tid & 15);
  const int kslot = (tid >> 4) & 3;
  const unsigned short* gA = A + (size_t)(tm * 256 + arow) * K_DIM + kslot * 8;
  const unsigned short* gB = B + (size_t)(tn * 256 + bcol) * K_DIM + kslot * 8;

#define STG(tt, bufi)                                                            \
  do {                                                                           \
    const unsigned short* _sa = gA + (size_t)(tt) * 32;                          \
    const unsigned short* _sb = gB + (size_t)(tt) * 32;                          \
    unsigned short* _da = smem + (bufi) * 8192 + dsto;                           \
    unsigned short* _db = smem + 32768 + (bufi) * 8192 + dsto;                   \
    gload_lds16(_sa, _da);                                                       \
    gload_lds16(_sa + (size_t)128 * K_DIM, _da + 4096);                          \
    gload_lds16(_sb, _db);                                                       \
    gload_lds16(_sb + (size_t)128 * K_DIM, _db + 4096);                          \
  } while (0)

  // lane-linear fragment reads: frag f at f*512 elems + l*8
  const int fr = l & 15, sb = l >> 4;
  const int abase = wr * 4096 + l * 8;  // + m*512
  const int bbase = wc * 2048 + l * 8;  // + n*512

  bf16x8 av[8], bv[4];
  f32x4 acc[8][4] = {};

#define TILE_BODY(cbuf)                                                          \
  {                                                                              \
    const unsigned short* _ca = smem + (cbuf) * 8192;                            \
    const unsigned short* _cb = smem + 32768 + (cbuf) * 8192;                    \
    _Pragma("unroll") for (int m = 0; m < 8; ++m)                                \
        av[m] = *(const bf16x8*)(_ca + abase + m * 512);                         \
    _Pragma("unroll") for (int n = 0; n < 4; ++n)                                \
        bv[n] = *(const bf16x8*)(_cb + bbase + n * 512);                         \
    __builtin_amdgcn_s_setprio(1);                                               \
    _Pragma("unroll") for (int m = 0; m < 8; ++m)                                \
    _Pragma("unroll") for (int n = 0; n < 4; ++n)                                \
        acc[m][n] = __builtin_amdgcn_mfma_f32_16x16x32_bf16(av[m], bv[n],        \
                                                            acc[m][n], 0, 0, 0); \
    __builtin_amdgcn_s_setprio(0);                                               \
  }

#define TILE(tt, cbuf, nbuf, VMN)                                                \
  {                                                                              \
    STG(tt + 3, nbuf);                                                           \
    TILE_BODY(cbuf);                                                             \
    SCHED0();                                                                    \
    asm volatile("s_waitcnt vmcnt(" VMN ")" ::: "memory");                       \
    BAR();                                                                       \
    SCHED0();                                                                    \
  }

  // ---- prologue: stage tiles 0,1,2 ----
  STG(0, 0);
  STG(1, 1);
  STG(2, 2);
  SCHED0();
  asm volatile("s_waitcnt vmcnt(8)" ::: "memory");  // tile 0 resident
  BAR();
  SCHED0();

  // ---- main: tiles 0..123 (stage through 126), 31 x 4-tile chunks ----
  for (int t4 = 0; t4 < 124; t4 += 4) {
    TILE(t4 + 0, 0, 3, "8");
    TILE(t4 + 1, 1, 0, "8");
    TILE(t4 + 2, 2, 1, "8");
    TILE(t4 + 3, 3, 2, "8");
  }

  // ---- peel tiles 124..127 ----
  STG(127, 3);
  TILE_BODY(0);
  SCHED0();
  asm volatile("s_waitcnt vmcnt(8)" ::: "memory");  // 125 resident
  BAR();
  SCHED0();
  TILE_BODY(1);
  SCHED0();
  asm volatile("s_waitcnt vmcnt(4)" ::: "memory");  // 126 resident
  BAR();
  SCHED0();
  TILE_BODY(2);
  SCHED0();
  asm volatile("s_waitcnt vmcnt(0)" ::: "memory");  // 127 resident
  BAR();
  SCHED0();
  TILE_BODY(3);

  // ---- epilogue: C/D layout col=lane&15, row=(lane>>4)*4+reg ----
  const int r0 = tm * 256 + wr * 128 + sb * 4;
  const int c0 = tn * 256 + wc * 64 + fr;
#pragma unroll
  for (int n = 0; n < 4; ++n) {
    const int col = c0 + n * 16;
    const float bvl = bias[col];
#pragma unroll
    for (int m = 0; m < 8; ++m) {
      const int row = r0 + m * 16;
#pragma unroll
      for (int jj = 0; jj < 4; ++jj)
        C[(size_t)(row + jj) * N_DIM + col] = acc[m][n][jj] + bvl;
    }
  }
}

extern "C" void kernel_launch(void* const* d_in, const int* in_sizes, int n_in,
                              void* d_out, int out_size, void* d_ws, size_t ws_size,
                              hipStream_t stream) {
  const float* x = (const float*)d_in[0];
  const int* qw = (const int*)d_in[1];
  const float* sc = (const float*)d_in[2];
  const float* zr = (const float*)d_in[3];
  const float* bs = (const float*)d_in[4];
  float* out = (float*)d_out;

  const size_t xb_bytes = (size_t)M_DIM * K_DIM * 2;
  const size_t wb_bytes = (size_t)N_DIM * K_DIM * 2;
  if (ws_size < xb_bytes + wb_bytes) return;

  unsigned short* xb = (unsigned short*)d_ws;
  unsigned short* wb = (unsigned short*)((char*)d_ws + xb_bytes);

  (void)hipFuncSetAttribute((const void*)gemm_kernel,
                            hipFuncAttributeMaxDynamicSharedMemorySize, 131072);

  cvt_x_kernel<<<(M_DIM * K_DIM / 8) / 256, 256, 0, stream>>>((const float4*)x, (u16x8*)xb);
  dequant_kernel<<<(N_DIM * K_DIM / 8) / 256, 256, 0, stream>>>((const int4*)qw, sc, zr,
                                                                (u16x8*)wb);
  gemm_kernel<<<(M_DIM / 256) * (N_DIM / 256), 512, 131072, stream>>>(xb, wb, bs, out);
}

// Round 10
// 710.336 us; speedup vs baseline: 1.2790x; 1.2790x over previous
//
#include <hip/hip_runtime.h>
#include <hip/hip_bf16.h>

// QuantizedLinear: out[m,o] = sum_k x[m,k] * (q[o,k]-z[o,g])*s[o,g] + b[o]
// M=8192, K=4096, N=11008. Pass1: dequant W->bf16 (row-major B^T), cvt x->bf16.
// Pass2: 256x256 bf16 GEMM (R6 structure), 2 phases/K-tile with HK-style
// read|BARRIER|MFMA handshake: reads+stages issue BEFORE the barrier, MFMAs
// after it, so barrier straggler-wait hides ds_read latency (kills the
// phase-start lgkm bubble).
//  P1: read A0,B0,B1 | stage A1,B0(t+1)->nxt | BAR1 | MFMA (0,0),(0,1)
//  P2: read A1 | stage A0,B1(t+2)->cur | vmcnt(4) | BAR2 | MFMA (1,1),(1,0)
// BAR1 separates P1 reads of cur from P2 stages into cur (WAR); vmcnt(4) at
// P2 drains exactly tile t+1 (4 loads stay in flight - T4 never-drain).
// T1 XCD swizzle, T2 LDS swizzle (inverse-swizzled global source), T5 setprio.

#define K_DIM 4096
#define N_DIM 11008
#define M_DIM 8192
#define NGRP 32

typedef __bf16 bf16x8 __attribute__((ext_vector_type(8)));
typedef float f32x4 __attribute__((ext_vector_type(4)));
typedef unsigned short u16x8 __attribute__((ext_vector_type(8)));

__device__ __forceinline__ unsigned short f2bf(float f) {
  unsigned u = __builtin_bit_cast(unsigned, f);
  return (unsigned short)((u + 0x7FFFu + ((u >> 16) & 1u)) >> 16);  // RNE
}

__device__ __forceinline__ void gload_lds16(const void* g, void* l) {
  __builtin_amdgcn_global_load_lds(
      (const __attribute__((address_space(1))) unsigned int*)(unsigned long long)g,
      (__attribute__((address_space(3))) unsigned int*)(unsigned int)(unsigned long long)l,
      16, 0, 0);
}

// ---- pass 1a: x fp32 -> bf16 ----
__global__ __launch_bounds__(256) void cvt_x_kernel(const float4* __restrict__ x4,
                                                    u16x8* __restrict__ xb) {
  int i = blockIdx.x * 256 + threadIdx.x;
  float4 a = x4[2 * i], b = x4[2 * i + 1];
  u16x8 r;
  r[0] = f2bf(a.x); r[1] = f2bf(a.y); r[2] = f2bf(a.z); r[3] = f2bf(a.w);
  r[4] = f2bf(b.x); r[5] = f2bf(b.y); r[6] = f2bf(b.z); r[7] = f2bf(b.w);
  xb[i] = r;
}

// ---- pass 1b: dequant W -> bf16 (row-major [N][K]) ----
__global__ __launch_bounds__(256) void dequant_kernel(const int4* __restrict__ q4,
                                                      const float* __restrict__ scales,
                                                      const float* __restrict__ zeros,
                                                      u16x8* __restrict__ wb) {
  int t = blockIdx.x * 256 + threadIdx.x;
  int o = t >> 9;
  int j8 = t & 511;
  int g = j8 >> 4;
  float s = scales[o * NGRP + g];
  float z = zeros[o * NGRP + g];
  float nzs = -z * s;
  int4 qa = q4[2 * t], qb = q4[2 * t + 1];
  u16x8 r;
  r[0] = f2bf(fmaf((float)qa.x, s, nzs));
  r[1] = f2bf(fmaf((float)qa.y, s, nzs));
  r[2] = f2bf(fmaf((float)qa.z, s, nzs));
  r[3] = f2bf(fmaf((float)qa.w, s, nzs));
  r[4] = f2bf(fmaf((float)qb.x, s, nzs));
  r[5] = f2bf(fmaf((float)qb.y, s, nzs));
  r[6] = f2bf(fmaf((float)qb.z, s, nzs));
  r[7] = f2bf(fmaf((float)qb.w, s, nzs));
  wb[t] = r;
}

// ---- pass 2: 256x256 bf16 GEMM, 2 phases / K-tile, read|BAR|MFMA handshake ----
#define BAR() __builtin_amdgcn_s_barrier()
#define SCHED0() __builtin_amdgcn_sched_barrier(0)

__global__ __launch_bounds__(512, 2) void gemm_kernel(const unsigned short* __restrict__ A,
                                                      const unsigned short* __restrict__ B,
                                                      const float* __restrict__ bias,
                                                      float* __restrict__ C) {
  extern __shared__ unsigned short smem[];
  unsigned short* sAb = smem;           // [2 buf][2 half][8192]
  unsigned short* sBb = smem + 32768;

  const int bid = blockIdx.x;
  // T1: 1376 blocks, 1376 % 8 == 0 -> simple bijective XCD swizzle.
  const int swz = (bid & 7) * 172 + (bid >> 3);
  const int tm = swz / 43, tn = swz % 43;

  const int tid = threadIdx.x;
  const int w = tid >> 6, l = tid & 63;
  const int wr = w >> 2, wc = w & 3;

  const int dsto = w * 512 + l * 8;            // LDS elem offset (wave base + lane*16B)
  const int gs = (l & 7) ^ (l >> 3);           // inverse T2 swizzle on global source slot
  const unsigned short* gA = A + (size_t)(tm * 256 + (tid >> 3)) * K_DIM + gs * 8;
  const unsigned short* gB = B + (size_t)(tn * 256 + (tid >> 3)) * K_DIM + gs * 8;

#define STG_A(tt, h, dst)                                                       \
  do {                                                                          \
    const unsigned short* _s = gA + (size_t)(h) * 128 * K_DIM + (tt) * 64;      \
    gload_lds16(_s, (dst) + dsto);                                              \
    gload_lds16(_s + 64 * K_DIM, (dst) + 4096 + dsto);                          \
  } while (0)
#define STG_B(tt, h, dst)                                                       \
  do {                                                                          \
    const unsigned short* _s = gB + (size_t)(h) * 128 * K_DIM + (tt) * 64;      \
    gload_lds16(_s, (dst) + dsto);                                              \
    gload_lds16(_s + 64 * K_DIM, (dst) + 4096 + dsto);                          \
  } while (0)

  // fragment read coords (16x16x32: lane row=l&15, k-chunk=l>>4, swizzled slots)
  const int fr = l & 15, sb = l >> 4, x7 = l & 7;
  const int abase = (wr * 64 + fr) * 64;
  const int bbase = (wc * 32 + fr) * 64;
  const int k0 = (sb ^ x7) * 8;
  const int k1 = ((sb + 4) ^ x7) * 8;

  bf16x8 av[4][2], bva[2][2], bvb[2][2];
  f32x4 acc[8][4] = {};

#define READ_A(half)                                                     \
  {                                                                      \
    _Pragma("unroll") for (int m = 0; m < 4; ++m) {                      \
      av[m][0] = *(const bf16x8*)((half) + abase + m * 1024 + k0);       \
      av[m][1] = *(const bf16x8*)((half) + abase + m * 1024 + k1);       \
    }                                                                    \
  }
#define READ_B(half, arr)                                                \
  {                                                                      \
    _Pragma("unroll") for (int n = 0; n < 2; ++n) {                      \
      arr[n][0] = *(const bf16x8*)((half) + bbase + n * 1024 + k0);      \
      arr[n][1] = *(const bf16x8*)((half) + bbase + n * 1024 + k1);      \
    }                                                                    \
  }
#define MFMA_Q(mh, nh, arr)                                                        \
  {                                                                                \
    __builtin_amdgcn_s_setprio(1);                                                 \
    _Pragma("unroll") for (int kk = 0; kk < 2; ++kk)                               \
    _Pragma("unroll") for (int m = 0; m < 4; ++m)                                  \
    _Pragma("unroll") for (int nn = 0; nn < 2; ++nn)                               \
      acc[(mh)*4 + m][(nh)*2 + nn] = __builtin_amdgcn_mfma_f32_16x16x32_bf16(      \
          av[m][kk], arr[nn][kk], acc[(mh)*4 + m][(nh)*2 + nn], 0, 0, 0);          \
    __builtin_amdgcn_s_setprio(0);                                                 \
  }

  // ---- prologue: tile0 all 4 halves + A0(1), B1(1) into buf1 ----
  STG_A(0, 0, sAb);
  STG_A(0, 1, sAb + 8192);
  STG_B(0, 0, sBb);
  STG_B(0, 1, sBb + 8192);
  STG_A(1, 0, sAb + 16384);
  STG_B(1, 1, sBb + 16384 + 8192);
  asm volatile("s_waitcnt vmcnt(4)" ::: "memory");
  BAR();
  SCHED0();

  for (int tt = 0; tt < 32; ++tt) {
    // ======== even tile t = 2*tt (cur = buf0, nxt = buf1) ========
    // P1: reads + stages BEFORE barrier; MFMA after (latency hidden by BAR wait)
    READ_A(sAb);
    READ_B(sBb, bva);
    READ_B(sBb + 8192, bvb);
    STG_A(2 * tt + 1, 1, sAb + 16384 + 8192);
    STG_B(2 * tt + 1, 0, sBb + 16384);
    SCHED0();
    BAR();
    SCHED0();
    MFMA_Q(0, 0, bva);
    MFMA_Q(0, 1, bvb);
    // P2
    READ_A(sAb + 8192);
    if (tt < 31) {
      STG_A(2 * tt + 2, 0, sAb);
      STG_B(2 * tt + 2, 1, sBb + 8192);
    }
    if (tt < 31) {
      asm volatile("s_waitcnt vmcnt(4)" ::: "memory");
    } else {
      asm volatile("s_waitcnt vmcnt(0)" ::: "memory");
    }
    SCHED0();
    BAR();
    SCHED0();
    MFMA_Q(1, 1, bvb);
    MFMA_Q(1, 0, bva);

    // ======== odd tile t = 2*tt+1 (cur = buf1, nxt = buf0) ========
    // P1
    READ_A(sAb + 16384);
    READ_B(sBb + 16384, bva);
    READ_B(sBb + 16384 + 8192, bvb);
    if (tt < 31) {
      STG_A(2 * tt + 2, 1, sAb + 8192);
      STG_B(2 * tt + 2, 0, sBb);
    }
    SCHED0();
    BAR();
    SCHED0();
    MFMA_Q(0, 0, bva);
    MFMA_Q(0, 1, bvb);
    // P2
    READ_A(sAb + 16384 + 8192);
    if (tt < 31) {
      STG_A(2 * tt + 3, 0, sAb + 16384);
      STG_B(2 * tt + 3, 1, sBb + 16384 + 8192);
    }
    if (tt < 31) {
      asm volatile("s_waitcnt vmcnt(4)" ::: "memory");
      SCHED0();
      BAR();
      SCHED0();
    }
    MFMA_Q(1, 1, bvb);
    MFMA_Q(1, 0, bva);
  }

  // ---- epilogue: C/D layout col=lane&15, row=(lane>>4)*4+reg ----
  const int r0 = tm * 256 + wr * 64 + sb * 4;
  const int c0 = tn * 256 + wc * 32 + fr;
#pragma unroll
  for (int n = 0; n < 4; ++n) {
    const int col = c0 + (n >> 1) * 128 + (n & 1) * 16;
    const float bv = bias[col];
#pragma unroll
    for (int mi = 0; mi < 8; ++mi) {
      const int row = r0 + (mi >> 2) * 128 + (mi & 3) * 16;
#pragma unroll
      for (int jj = 0; jj < 4; ++jj)
        C[(size_t)(row + jj) * N_DIM + col] = acc[mi][n][jj] + bv;
    }
  }
}

extern "C" void kernel_launch(void* const* d_in, const int* in_sizes, int n_in,
                              void* d_out, int out_size, void* d_ws, size_t ws_size,
                              hipStream_t stream) {
  const float* x = (const float*)d_in[0];
  const int* qw = (const int*)d_in[1];
  const float* sc = (const float*)d_in[2];
  const float* zr = (const float*)d_in[3];
  const float* bs = (const float*)d_in[4];
  float* out = (float*)d_out;

  const size_t xb_bytes = (size_t)M_DIM * K_DIM * 2;
  const size_t wb_bytes = (size_t)N_DIM * K_DIM * 2;
  if (ws_size < xb_bytes + wb_bytes) return;

  unsigned short* xb = (unsigned short*)d_ws;
  unsigned short* wb = (unsigned short*)((char*)d_ws + xb_bytes);

  (void)hipFuncSetAttribute((const void*)gemm_kernel,
                            hipFuncAttributeMaxDynamicSharedMemorySize, 131072);

  cvt_x_kernel<<<(M_DIM * K_DIM / 8) / 256, 256, 0, stream>>>((const float4*)x, (u16x8*)xb);
  dequant_kernel<<<(N_DIM * K_DIM / 8) / 256, 256, 0, stream>>>((const int4*)qw, sc, zr,
                                                                (u16x8*)wb);
  gemm_kernel<<<(M_DIM / 256) * (N_DIM / 256), 512, 131072, stream>>>(xb, wb, bs, out);
}